// Round 15
// baseline (1282.035 us; speedup 1.0000x reference)
//
#include <hip/hip_runtime.h>
#include <hip/hip_bf16.h>
#include <stdint.h>
#include <stddef.h>

#define E_ 8
#define C_ 4096
#define H_ 1024
#define I_ 4096

typedef short s16;
typedef __attribute__((ext_vector_type(8))) short short8;    // 8 bf16 (4 VGPRs)
typedef __attribute__((ext_vector_type(4))) short short4v;   // 4 bf16 (8B)
typedef __attribute__((ext_vector_type(16))) float f32x16;   // 32x32 C/D frag
typedef __attribute__((ext_vector_type(4))) float float4v;

__device__ __forceinline__ s16 f2bf(float f) {
  union { __hip_bfloat16 h; s16 s; } u;
  u.h = __float2bfloat16(f);
  return u.s;
}

// async global->LDS, 16B per lane. LDS dest is wave-uniform base + lane*16.
__device__ __forceinline__ void gload16(const void* gsrc, void* ldst) {
  __builtin_amdgcn_global_load_lds(
      (const __attribute__((address_space(1))) void*)gsrc,
      (__attribute__((address_space(3))) void*)ldst, 16, 0, 0);
}

// ---------------------------------------------------------------------------
// prep: expert = blockIdx.y   (FROZEN since r3; ~HBM roofline)
// z=0: x fp32 -> bf16
// z=1: Wg [H][I] -> interleaved Wgu rows (gate block)   [2I][H] bf16
// z=2: Wu -> interleaved Wgu rows (up block)
// z=3: Wd [I][H] -> WdT [H][I] bf16
// Interleave: real col i -> row (i&~15)*2 + (i&15) (+16 for up).
// ---------------------------------------------------------------------------
__global__ __launch_bounds__(256) void prep_kernel(
    const float* __restrict__ x, const float* __restrict__ Wg,
    const float* __restrict__ Wu, const float* __restrict__ Wd,
    s16* __restrict__ xb, s16* __restrict__ Wgu, s16* __restrict__ WdT)
{
  __shared__ float tile[64][65];
  const int t = threadIdx.x;
  const int z = blockIdx.z;
  const size_t e = blockIdx.y;

  if (z == 0) {
    size_t base = e * (size_t)C_ * H_ + ((size_t)blockIdx.x * 256 + t) * 16;
    for (int j = 0; j < 16; j += 8) {
      float4v v0 = *(const float4v*)(x + base + j);
      float4v v1 = *(const float4v*)(x + base + j + 4);
      s16 o[8];
      o[0] = f2bf(v0[0]); o[1] = f2bf(v0[1]); o[2] = f2bf(v0[2]); o[3] = f2bf(v0[3]);
      o[4] = f2bf(v1[0]); o[5] = f2bf(v1[1]); o[6] = f2bf(v1[2]); o[7] = f2bf(v1[3]);
      *(short8*)(xb + base + j) = *(short8*)o;
    }
    return;
  }

  const float* src; int Cc;
  if (z == 1)      { src = Wg + e * (size_t)H_ * I_; Cc = I_; }
  else if (z == 2) { src = Wu + e * (size_t)H_ * I_; Cc = I_; }
  else             { src = Wd + e * (size_t)H_ * I_; Cc = H_; }

  const int tpr  = Cc >> 6;
  const int trow = blockIdx.x / tpr;
  const int tcol = blockIdx.x % tpr;

  const int c = t & 63, rq = t >> 6;
  for (int i = 0; i < 16; ++i) {
    int r = rq * 16 + i;
    tile[r][c] = src[(size_t)(trow * 64 + r) * Cc + tcol * 64 + c];
  }
  __syncthreads();

  const int ro = t >> 2, cb = (t & 3) * 16;
  s16 o[16];
  for (int j = 0; j < 16; ++j) o[j] = f2bf(tile[cb + j][ro]);

  const int i0 = tcol * 64 + ro;
  s16* op;
  if (z == 3) {
    op = WdT + e * (size_t)H_ * I_ + (size_t)i0 * I_ + trow * 64 + cb;
  } else {
    int grow = ((i0 & ~15) << 1) + (i0 & 15) + ((z == 2) ? 16 : 0);
    op = Wgu + e * (size_t)2 * I_ * H_ + (size_t)grow * H_ + trow * 64 + cb;
  }
  *(short8*)op       = *(short8*)&o[0];
  *(short8*)(op + 8) = *(short8*)&o[8];
}

// ===========================================================================
// 32x32x16 fragment-block GEMM core.
// LDS layout per 32 KB tile (A or B): 32 fragment-blocks of 1 KB, indexed
// fb = kstep*8 + rblock (kstep 0..3 = K16 step; rblock 0..7 = 32-row group).
// Within a block, granule w = (kg<<5)|row32 -> lane l reads base + l*16:
// LINEAR -> conflict-free by construction. Staging: gload_lds dest is
// linear (wave-uniform base + lane*16); the per-lane GLOBAL source supplies
// (row = 32*wave + (lane&31), col = kt*64 + i*16 + 8*(lane>>5)) for inst i
// -> exact bijection with the reader (verified element-wise).
// MFMA: swapped operands mfma(bf, af) -> D^T: out-row = base + (lane&31),
// out-col = base_n + (reg&3) + 8*(reg>>2) + 4*(lane>>5)  [m74/m101 map,
// swap validated r10 via absmax].
// Schedule: 4 phases per 2 K-tiles; ledger == r12's (absmax-passed):
// slots t1.A@ph1-top, t2.B@ph2-tail, t2.A@ph3-top, t3.B@ph4-tail;
// VMW4 at ph2/ph4 keeps exactly the newest 4-load group.
// ===========================================================================
#define VMW4 asm volatile("s_waitcnt vmcnt(4)" ::: "memory");

#define LDA32(B, KS, MF) \
  (*(const short8*)(shm + (B)*16384 + (KS)*4096 + (aR + (MF))*512 + l8))
#define LDB32(B, KS, NF) \
  (*(const short8*)(shm + 32768 + (B)*16384 + (KS)*4096 + (bR + (NF))*512 + l8))

#define PHASE32(B, KS, TOPSTMT, TAILSTMT)                                    \
  {                                                                          \
    short8 a00 = LDA32(B, (KS),   0), a01 = LDA32(B, (KS),   1);             \
    short8 a02 = LDA32(B, (KS),   2), a03 = LDA32(B, (KS),   3);             \
    short8 a10 = LDA32(B, (KS)+1, 0), a11 = LDA32(B, (KS)+1, 1);             \
    short8 a12 = LDA32(B, (KS)+1, 2), a13 = LDA32(B, (KS)+1, 3);             \
    short8 b00 = LDB32(B, (KS),   0), b01 = LDB32(B, (KS),   1);             \
    short8 b10 = LDB32(B, (KS)+1, 0), b11 = LDB32(B, (KS)+1, 1);             \
    TOPSTMT                                                                  \
    __builtin_amdgcn_sched_barrier(0);                                       \
    __builtin_amdgcn_s_barrier();                                            \
    asm volatile("s_waitcnt lgkmcnt(0)" ::: "memory");                       \
    __builtin_amdgcn_sched_barrier(0);                                       \
    __builtin_amdgcn_s_setprio(1);                                           \
    acc[0][0] = __builtin_amdgcn_mfma_f32_32x32x16_bf16(b00, a00, acc[0][0], 0, 0, 0); \
    acc[0][1] = __builtin_amdgcn_mfma_f32_32x32x16_bf16(b01, a00, acc[0][1], 0, 0, 0); \
    acc[1][0] = __builtin_amdgcn_mfma_f32_32x32x16_bf16(b00, a01, acc[1][0], 0, 0, 0); \
    acc[1][1] = __builtin_amdgcn_mfma_f32_32x32x16_bf16(b01, a01, acc[1][1], 0, 0, 0); \
    acc[2][0] = __builtin_amdgcn_mfma_f32_32x32x16_bf16(b00, a02, acc[2][0], 0, 0, 0); \
    acc[2][1] = __builtin_amdgcn_mfma_f32_32x32x16_bf16(b01, a02, acc[2][1], 0, 0, 0); \
    acc[3][0] = __builtin_amdgcn_mfma_f32_32x32x16_bf16(b00, a03, acc[3][0], 0, 0, 0); \
    acc[3][1] = __builtin_amdgcn_mfma_f32_32x32x16_bf16(b01, a03, acc[3][1], 0, 0, 0); \
    acc[0][0] = __builtin_amdgcn_mfma_f32_32x32x16_bf16(b10, a10, acc[0][0], 0, 0, 0); \
    acc[0][1] = __builtin_amdgcn_mfma_f32_32x32x16_bf16(b11, a10, acc[0][1], 0, 0, 0); \
    acc[1][0] = __builtin_amdgcn_mfma_f32_32x32x16_bf16(b10, a11, acc[1][0], 0, 0, 0); \
    acc[1][1] = __builtin_amdgcn_mfma_f32_32x32x16_bf16(b11, a11, acc[1][1], 0, 0, 0); \
    acc[2][0] = __builtin_amdgcn_mfma_f32_32x32x16_bf16(b10, a12, acc[2][0], 0, 0, 0); \
    acc[2][1] = __builtin_amdgcn_mfma_f32_32x32x16_bf16(b11, a12, acc[2][1], 0, 0, 0); \
    acc[3][0] = __builtin_amdgcn_mfma_f32_32x32x16_bf16(b10, a13, acc[3][0], 0, 0, 0); \
    acc[3][1] = __builtin_amdgcn_mfma_f32_32x32x16_bf16(b11, a13, acc[3][1], 0, 0, 0); \
    __builtin_amdgcn_s_setprio(0);                                           \
    __builtin_amdgcn_sched_barrier(0);                                       \
    TAILSTMT                                                                 \
    __builtin_amdgcn_s_barrier();                                            \
  }

// ===========================================================================
// gemm_gu: gateup. 256x256 tile, BK=64, 8 waves, 128 KiB LDS dbuf,
// 32x32x16 fragment-block core, r4 fetch-optimal XCD mapping.
// ===========================================================================
__global__ __launch_bounds__(512, 2) void gemm_gu(
    const s16* __restrict__ Abase, const s16* __restrict__ Bbase,
    s16* __restrict__ HOut)
{
  constexpr int K  = H_;     // 1024
  constexpr int NB = 2 * I_; // 8192
  constexpr int NT = K / 64; // 16

  __shared__ s16 shm[65536];

  const int tid  = threadIdx.x;
  const int wave = tid >> 6, lane = tid & 63;
  const int e    = blockIdx.z;

  // r4 fetch-optimal per-XCD partition: 8bn x 8bm per XCD, bn-inner.
  const int bid = blockIdx.x;
  const int xcd = bid & 7;
  const int idx = bid >> 3;
  const int bn = (xcd & 3) * 8 + (idx & 7);
  const int bm = (xcd >> 2) * 8 + (idx >> 3);

  const s16* A = Abase + (size_t)e * C_ * K + (size_t)bm * 256 * K;
  const s16* B = Bbase + (size_t)e * NB * K + (size_t)bn * 256 * K;

  const int wm = (wave >> 2) * 128;
  const int wn = (wave & 3) * 64;
  const int aR = (wave >> 2) * 4;     // A rblock base
  const int bR = (wave & 3) * 2;      // B rblock base
  const int l8 = lane * 8;            // linear fragment read offset (elems)
  const int lrow = lane & 31;
  const int lkg  = (lane >> 5) * 8;

  // staging: inst i covers kstep i; wave covers rblock=wave (rows 32w..+31)
  auto stageA = [&](int kt, int b) {
    #pragma unroll
    for (int i = 0; i < 4; ++i)
      gload16(A + (size_t)(wave * 32 + lrow) * K + kt * 64 + i * 16 + lkg,
              shm + b * 16384 + i * 4096 + wave * 512);
  };
  auto stageB = [&](int kt, int b) {
    #pragma unroll
    for (int i = 0; i < 4; ++i)
      gload16(B + (size_t)(wave * 32 + lrow) * K + kt * 64 + i * 16 + lkg,
              shm + 32768 + b * 16384 + i * 4096 + wave * 512);
  };

  f32x16 acc[4][2];
  #pragma unroll
  for (int m = 0; m < 4; ++m)
    #pragma unroll
    for (int n = 0; n < 2; ++n)
      #pragma unroll
      for (int q = 0; q < 16; ++q) acc[m][n][q] = 0.f;

  // prologue (r12 ledger): tile0 fully + t1.B; VMW4 keeps t1.B in flight
  stageB(0, 0);
  stageA(0, 0);
  stageB(1, 1);
  VMW4
  __builtin_amdgcn_sched_barrier(0);
  __builtin_amdgcn_s_barrier();

  for (int i = 0; i < NT / 2; ++i) {
    const int t1 = 2 * i + 1;
    const int t2 = (2 * i + 2 < NT) ? (2 * i + 2) : (NT - 1);
    const int t3 = (2 * i + 3 < NT) ? (2 * i + 3) : (NT - 1);
    PHASE32(0, 0, { stageA(t1, 1); }, )
    PHASE32(0, 2, {}, { stageB(t2, 0); VMW4 })
    PHASE32(1, 0, { stageA(t2, 0); }, )
    PHASE32(1, 2, {}, { stageB(t3, 1); VMW4 })
  }

  // epilogue: D^T 32x32 map; gate = regs 0..7, up = regs 8..15 (same i).
  s16* Hp = HOut + (size_t)e * C_ * I_;
  const int ib0 = bn * 128 + (wn >> 1);
  const int lkh4 = (lane >> 5) * 4;
  #pragma unroll
  for (int MF = 0; MF < 4; ++MF) {
    const int row = bm * 256 + wm + MF * 32 + lrow;
    #pragma unroll
    for (int NF = 0; NF < 2; ++NF) {
      #pragma unroll
      for (int q = 0; q < 2; ++q) {
        const int col = ib0 + NF * 16 + q * 8 + lkh4;
        s16 o4[4];
        #pragma unroll
        for (int j = 0; j < 4; ++j) {
          float g = acc[MF][NF][4 * q + j];
          float u = acc[MF][NF][8 + 4 * q + j];
          float sg = 1.0f / (1.0f + __expf(-g));
          o4[j] = f2bf(g * sg * u);
        }
        *(short4v*)(Hp + (size_t)row * I_ + col) = *(short4v*)o4;
      }
    }
  }
}

// ===========================================================================
// gemm_dn: down GEMM — same 32x32 fragment-block core; r14 grid/mapping.
// ===========================================================================
__global__ __launch_bounds__(512, 2) void gemm_dn(
    const s16* __restrict__ Abase, const s16* __restrict__ Bbase,
    float* __restrict__ FOut)
{
  constexpr int K  = I_;     // 4096
  constexpr int NB = H_;     // 1024
  constexpr int NT = K / 64; // 64
  constexpr int TN = NB / 256;
  constexpr int TM = C_ / 256;
  constexpr int NWG = TM * TN;

  __shared__ s16 shm[65536];

  const int tid  = threadIdx.x;
  const int wave = tid >> 6, lane = tid & 63;
  const int e    = blockIdx.z;

  const int bid = blockIdx.x;
  const int swz = (bid & 7) * (NWG / 8) + (bid >> 3);
  const int bm = swz / TN, bn = swz % TN;

  const s16* A = Abase + (size_t)e * C_ * K + (size_t)bm * 256 * K;
  const s16* B = Bbase + (size_t)e * NB * K + (size_t)bn * 256 * K;

  const int wm = (wave >> 2) * 128;
  const int wn = (wave & 3) * 64;
  const int aR = (wave >> 2) * 4;
  const int bR = (wave & 3) * 2;
  const int l8 = lane * 8;
  const int lrow = lane & 31;
  const int lkg  = (lane >> 5) * 8;

  auto stageA = [&](int kt, int b) {
    #pragma unroll
    for (int i = 0; i < 4; ++i)
      gload16(A + (size_t)(wave * 32 + lrow) * K + kt * 64 + i * 16 + lkg,
              shm + b * 16384 + i * 4096 + wave * 512);
  };
  auto stageB = [&](int kt, int b) {
    #pragma unroll
    for (int i = 0; i < 4; ++i)
      gload16(B + (size_t)(wave * 32 + lrow) * K + kt * 64 + i * 16 + lkg,
              shm + 32768 + b * 16384 + i * 4096 + wave * 512);
  };

  f32x16 acc[4][2];
  #pragma unroll
  for (int m = 0; m < 4; ++m)
    #pragma unroll
    for (int n = 0; n < 2; ++n)
      #pragma unroll
      for (int q = 0; q < 16; ++q) acc[m][n][q] = 0.f;

  stageB(0, 0);
  stageA(0, 0);
  stageB(1, 1);
  VMW4
  __builtin_amdgcn_sched_barrier(0);
  __builtin_amdgcn_s_barrier();

  for (int i = 0; i < NT / 2; ++i) {
    const int t1 = 2 * i + 1;
    const int t2 = (2 * i + 2 < NT) ? (2 * i + 2) : (NT - 1);
    const int t3 = (2 * i + 3 < NT) ? (2 * i + 3) : (NT - 1);
    PHASE32(0, 0, { stageA(t1, 1); }, )
    PHASE32(0, 2, {}, { stageB(t2, 0); VMW4 })
    PHASE32(1, 0, { stageA(t2, 0); }, )
    PHASE32(1, 2, {}, { stageB(t3, 1); VMW4 })
  }

  // epilogue: D^T 32x32 map, float4 stores (reg quads = 4 consecutive cols)
  float* Op = FOut + (size_t)e * C_ * H_;
  const int lkh4 = (lane >> 5) * 4;
  #pragma unroll
  for (int MF = 0; MF < 4; ++MF) {
    const int row = bm * 256 + wm + MF * 32 + lrow;
    #pragma unroll
    for (int NF = 0; NF < 2; ++NF) {
      #pragma unroll
      for (int q = 0; q < 4; ++q) {
        const int col = bn * 256 + wn + NF * 32 + q * 8 + lkh4;
        float4v v;
        v[0] = acc[MF][NF][4 * q + 0];
        v[1] = acc[MF][NF][4 * q + 1];
        v[2] = acc[MF][NF][4 * q + 2];
        v[3] = acc[MF][NF][4 * q + 3];
        *(float4v*)(Op + (size_t)row * H_ + col) = v;
      }
    }
  }
}

// ---------------------------------------------------------------------------
extern "C" void kernel_launch(void* const* d_in, const int* in_sizes, int n_in,
                              void* d_out, int out_size, void* d_ws, size_t ws_size,
                              hipStream_t stream) {
  const float* x  = (const float*)d_in[0];
  const float* Wg = (const float*)d_in[1];
  const float* Wu = (const float*)d_in[2];
  const float* Wd = (const float*)d_in[3];
  float* out = (float*)d_out;

  const size_t szX  = (size_t)C_ * H_;
  const size_t szGU = (size_t)2 * I_ * H_;
  const size_t szWd = (size_t)H_ * I_;
  const size_t szH  = (size_t)C_ * I_;

  const size_t needFull = 2 * E_ * (szX + szGU + szWd + szH);   // 512 MiB

  constexpr int GU_BLK = (C_ / 256) * (2 * I_ / 256);   // 512
  constexpr int DN_BLK = (C_ / 256) * (H_ / 256);       // 64

  if (ws_size >= needFull) {
    s16* xb  = (s16*)d_ws;                  // [E][C][H]
    s16* Wgu = xb  + E_ * szX;              // [E][2I][H] interleaved
    s16* WdT = Wgu + E_ * szGU;             // [E][H][I]
    s16* hbf = WdT + E_ * szWd;             // [E][C][I]

    prep_kernel<<<dim3(1024, E_, 4), 256, 0, stream>>>(
        x, Wg, Wu, Wd, xb, Wgu, WdT);
    gemm_gu<<<dim3(GU_BLK, 1, E_), 512, 0, stream>>>(
        xb, Wgu, hbf);
    gemm_dn<<<dim3(DN_BLK, 1, E_), 512, 0, stream>>>(
        hbf, WdT, out);
  } else {
    // per-expert fallback (67 MiB workspace), same kernels with gridZ=1
    s16* xb  = (s16*)d_ws;
    s16* Wgu = xb  + szX;
    s16* WdT = Wgu + szGU;
    s16* hbf = WdT + szWd;

    for (int e = 0; e < E_; ++e) {
      prep_kernel<<<dim3(1024, 1, 4), 256, 0, stream>>>(
          x + e * szX, Wg + e * szWd, Wu + e * szWd, Wd + e * szWd,
          xb, Wgu, WdT);
      gemm_gu<<<dim3(GU_BLK, 1, 1), 512, 0, stream>>>(
          xb, Wgu, hbf);
      gemm_dn<<<dim3(DN_BLK, 1, 1), 512, 0, stream>>>(
          hbf, WdT, out + e * szX);
    }
  }
}